// Round 4
// baseline (5953.979 us; speedup 1.0000x reference)
//
#include <hip/hip_runtime.h>
#include <hip/hip_bf16.h>
#include <math.h>

typedef long long i64;
typedef __hip_bfloat16 bf16;

#define HW 4096
#define KVC 960
#define BATCH 8

__device__ __forceinline__ float bf2f(unsigned short u) {
    union { unsigned int i; float f; } c; c.i = ((unsigned int)u) << 16; return c.f;
}
__device__ __forceinline__ float tof(bf16 v) { return __bfloat162float(v); }

__device__ __forceinline__ float4 load4(const float* p) { return *(const float4*)p; }
__device__ __forceinline__ float4 load4(const bf16* p) {
    ushort4 u = *(const ushort4*)p;
    float4 f; f.x = bf2f(u.x); f.y = bf2f(u.y); f.z = bf2f(u.z); f.w = bf2f(u.w);
    return f;
}

__device__ __forceinline__ void store1(float* p, float v) { *p = v; }
__device__ __forceinline__ void store1(bf16* p, float v) { *p = __float2bfloat16(v); }

// ---------------------------------------------------------------------------
// Generic batched tiled GEMM: C[bz] = alpha * A[bz] * B[bz] (optionally B^T)
// A: (M,K) row-major, B: (K,N) row-major (or (N,K) if TRANS_B), C: (M,N).
// M,N multiples of 64; K multiple of 16. 256 threads, 64x64 tile, 4x4/thread.
// TA/TB/TC may be float or bf16 (fp32 accumulate; convert at LDS/store edge).
// ---------------------------------------------------------------------------
template<typename TA, typename TB, typename TC, bool TRANS_B>
__global__ __launch_bounds__(256)
void gemm_kernel(const TA* __restrict__ A, i64 aBatch,
                 const TB* __restrict__ Bm, i64 bBatch,
                 TC* __restrict__ C, i64 cBatch,
                 int M, int N, int K, float alpha)
{
    __shared__ float As[16][64];
    __shared__ float Bs[16][64];
    const int bz = blockIdx.z;
    const TA* Ab = A + (i64)bz * aBatch;
    const TB* Bb = Bm + (i64)bz * bBatch;
    const int m0 = blockIdx.y * 64;
    const int n0 = blockIdx.x * 64;
    const int tid = threadIdx.x;
    const int tx = tid & 15, ty = tid >> 4;
    const int ar = tid >> 2;          // 0..63
    const int ac = (tid & 3) << 2;    // 0,4,8,12
    const int br = tid >> 4;          // 0..15
    const int bc = (tid & 15) << 2;   // 0..60

    float acc[4][4] = {};

    for (int k0 = 0; k0 < K; k0 += 16) {
        float4 av = load4(Ab + (i64)(m0 + ar) * K + (k0 + ac));
        As[ac+0][ar] = av.x; As[ac+1][ar] = av.y; As[ac+2][ar] = av.z; As[ac+3][ar] = av.w;
        if constexpr (TRANS_B) {
            float4 bv = load4(Bb + (i64)(n0 + ar) * K + (k0 + ac));
            Bs[ac+0][ar] = bv.x; Bs[ac+1][ar] = bv.y; Bs[ac+2][ar] = bv.z; Bs[ac+3][ar] = bv.w;
        } else {
            float4 bv = load4(Bb + (i64)(k0 + br) * N + (n0 + bc));
            Bs[br][bc+0] = bv.x; Bs[br][bc+1] = bv.y; Bs[br][bc+2] = bv.z; Bs[br][bc+3] = bv.w;
        }
        __syncthreads();
        #pragma unroll
        for (int kk = 0; kk < 16; ++kk) {
            float a[4], b[4];
            #pragma unroll
            for (int i = 0; i < 4; ++i) a[i] = As[kk][ty*4+i];
            #pragma unroll
            for (int j = 0; j < 4; ++j) b[j] = Bs[kk][tx*4+j];
            #pragma unroll
            for (int i = 0; i < 4; ++i)
                #pragma unroll
                for (int j = 0; j < 4; ++j)
                    acc[i][j] = fmaf(a[i], b[j], acc[i][j]);
        }
        __syncthreads();
    }

    const i64 cb = (i64)bz * cBatch;
    #pragma unroll
    for (int i = 0; i < 4; ++i) {
        const int m = m0 + ty*4 + i;
        const i64 row = cb + (i64)m * N + (n0 + tx*4);
        #pragma unroll
        for (int j = 0; j < 4; ++j)
            store1(C + row + j, alpha * acc[i][j]);
    }
}

// ---------------------------------------------------------------------------
// Depthwise 3x3 SAME (cross-correlation), NCHW 64x64 images. fp32 weights,
// bf16 activations in/out (fp32 math).
// ---------------------------------------------------------------------------
__global__ __launch_bounds__(256)
void dw3x3(const bf16* __restrict__ in, const float* __restrict__ w,
           bf16* __restrict__ out, int C)
{
    const int idx = blockIdx.x * 256 + threadIdx.x;   // over BATCH*C*HW
    const int p = idx & 4095;
    const int bch = idx >> 12;
    const int c = bch % C;
    const int x = p & 63, y = p >> 6;
    const float* wp = w + c * 9;
    const bf16* ip = in + (i64)bch * HW;
    float s = 0.f;
    #pragma unroll
    for (int dy = -1; dy <= 1; ++dy) {
        const int yy = y + dy;
        if (yy < 0 || yy > 63) continue;
        #pragma unroll
        for (int dx = -1; dx <= 1; ++dx) {
            const int xx = x + dx;
            if (xx < 0 || xx > 63) continue;
            s = fmaf(wp[(dy+1)*3 + (dx+1)], tof(ip[yy*64 + xx]), s);
        }
    }
    out[idx] = __float2bfloat16(s);
}

// ---------------------------------------------------------------------------
// Grouped 3x3 SAME, groups = C/2 (2 in-ch, 2 out-ch per group). w: (C,2,3,3)
// ---------------------------------------------------------------------------
__global__ __launch_bounds__(256)
void gconv3x3(const bf16* __restrict__ in, const float* __restrict__ w,
              bf16* __restrict__ out, int C)
{
    const int idx = blockIdx.x * 256 + threadIdx.x;   // over BATCH*C*HW
    const int p = idx & 4095;
    const int bch = idx >> 12;
    const int c = bch % C;      // output channel
    const int b = bch / C;
    const int x = p & 63, y = p >> 6;
    const float* wp = w + c * 18;
    const bf16* i0 = in + ((i64)b * C + (c & ~1)) * HW;
    float s = 0.f;
    #pragma unroll
    for (int j = 0; j < 2; ++j) {
        #pragma unroll
        for (int dy = -1; dy <= 1; ++dy) {
            const int yy = y + dy;
            if (yy < 0 || yy > 63) continue;
            #pragma unroll
            for (int dx = -1; dx <= 1; ++dx) {
                const int xx = x + dx;
                if (xx < 0 || xx > 63) continue;
                s = fmaf(wp[j*9 + (dy+1)*3 + (dx+1)], tof(i0[(i64)j*HW + yy*64 + xx]), s);
            }
        }
    }
    out[idx] = __float2bfloat16(s);
}

// ---------------------------------------------------------------------------
// Per-row L2 normalize (rows of length 4096), bf16 in place.
// ---------------------------------------------------------------------------
__global__ __launch_bounds__(256)
void l2norm_rows(bf16* __restrict__ x)
{
    const i64 base = (i64)blockIdx.x * HW;
    float ss = 0.f;
    for (int i = threadIdx.x; i < HW; i += 256) {
        const float v = tof(x[base + i]);
        ss = fmaf(v, v, ss);
    }
    #pragma unroll
    for (int o = 32; o > 0; o >>= 1) ss += __shfl_down(ss, o);
    __shared__ float red[4];
    __shared__ float sinv;
    const int lane = threadIdx.x & 63, wid = threadIdx.x >> 6;
    if (lane == 0) red[wid] = ss;
    __syncthreads();
    if (threadIdx.x == 0) {
        float t = red[0] + red[1] + red[2] + red[3];
        t = fmaxf(sqrtf(t), 1e-12f);
        sinv = 1.0f / t;
    }
    __syncthreads();
    const float inv = sinv;
    for (int i = threadIdx.x; i < HW; i += 256)
        x[base + i] = __float2bfloat16(tof(x[base + i]) * inv);
}

// ---------------------------------------------------------------------------
// Instance-norm stats over (c*KV) elements per batch: writes mu, rsqrt(var+eps)
// ---------------------------------------------------------------------------
__global__ __launch_bounds__(256)
void inorm_stats(const float* __restrict__ a, float* __restrict__ stats, int n)
{
    const i64 base = (i64)blockIdx.x * n;
    float s = 0.f, s2 = 0.f;
    for (int i = threadIdx.x; i < n; i += 256) {
        const float v = a[base + i];
        s += v;
        s2 = fmaf(v, v, s2);
    }
    #pragma unroll
    for (int o = 32; o > 0; o >>= 1) {
        s  += __shfl_down(s, o);
        s2 += __shfl_down(s2, o);
    }
    __shared__ float r1[4], r2[4];
    const int lane = threadIdx.x & 63, wid = threadIdx.x >> 6;
    if (lane == 0) { r1[wid] = s; r2[wid] = s2; }
    __syncthreads();
    if (threadIdx.x == 0) {
        const float S  = r1[0] + r1[1] + r1[2] + r1[3];
        const float S2 = r2[0] + r2[1] + r2[2] + r2[3];
        const float mu = S / (float)n;
        const float var = S2 / (float)n - mu * mu;
        stats[blockIdx.x * 2 + 0] = mu;
        stats[blockIdx.x * 2 + 1] = rsqrtf(var + 1e-5f);
    }
}

// ---------------------------------------------------------------------------
// Row softmax over KV=960 after instance-norm transform, in place (fp32).
// ---------------------------------------------------------------------------
__global__ __launch_bounds__(256)
void softmax_rows(float* __restrict__ a, const float* __restrict__ stats, int c)
{
    const int row = blockIdx.x;
    const int b = row / c;
    const i64 base = (i64)row * KVC;
    const float mu = stats[b*2 + 0];
    const float rs = stats[b*2 + 1];
    float vals[4];
    float mx = -1e30f;
    #pragma unroll
    for (int t = 0; t < 4; ++t) {
        const int i = threadIdx.x + t * 256;
        float v = -1e30f;
        if (i < KVC) v = (a[base + i] - mu) * rs;
        vals[t] = v;
        mx = fmaxf(mx, v);
    }
    #pragma unroll
    for (int o = 32; o > 0; o >>= 1) mx = fmaxf(mx, __shfl_down(mx, o));
    __shared__ float red[4];
    __shared__ float bmx, bsum;
    const int lane = threadIdx.x & 63, wid = threadIdx.x >> 6;
    if (lane == 0) red[wid] = mx;
    __syncthreads();
    if (threadIdx.x == 0) bmx = fmaxf(fmaxf(red[0], red[1]), fmaxf(red[2], red[3]));
    __syncthreads();
    const float M = bmx;
    float se = 0.f;
    #pragma unroll
    for (int t = 0; t < 4; ++t) {
        const int i = threadIdx.x + t * 256;
        if (i < KVC) { vals[t] = expf(vals[t] - M); se += vals[t]; }
    }
    #pragma unroll
    for (int o = 32; o > 0; o >>= 1) se += __shfl_down(se, o);
    if (lane == 0) red[wid] = se;
    __syncthreads();
    if (threadIdx.x == 0) bsum = red[0] + red[1] + red[2] + red[3];
    __syncthreads();
    const float S = bsum;
    #pragma unroll
    for (int t = 0; t < 4; ++t) {
        const int i = threadIdx.x + t * 256;
        if (i < KVC) a[base + i] = vals[t] / S;
    }
}

// ---------------------------------------------------------------------------
extern "C" void kernel_launch(void* const* d_in, const int* in_sizes, int n_in,
                              void* d_out, int out_size, void* d_ws, size_t ws_size,
                              hipStream_t stream)
{
    (void)in_sizes; (void)n_in; (void)out_size; (void)ws_size;

    const float* emb[4]  = {(const float*)d_in[0], (const float*)d_in[1],
                            (const float*)d_in[2], (const float*)d_in[3]};
    const float* emb_all = (const float*)d_in[4];
    const float* wm[4]   = {(const float*)d_in[5], (const float*)d_in[8],
                            (const float*)d_in[11], (const float*)d_in[14]};
    const float* wq[4]   = {(const float*)d_in[6], (const float*)d_in[9],
                            (const float*)d_in[12], (const float*)d_in[15]};
    const float* wp[4]   = {(const float*)d_in[7], (const float*)d_in[10],
                            (const float*)d_in[13], (const float*)d_in[16]};
    const float* wmk = (const float*)d_in[17];
    const float* wmv = (const float*)d_in[18];
    const float* wk  = (const float*)d_in[19];
    const float* wv  = (const float*)d_in[20];
    float* out = (float*)d_out;   // DISCRIMINATOR: fp32 output this round

    // workspace layout (bf16 unless noted) — ~238 MB total:
    bf16* kb = (bf16*)d_ws;
    bf16* vb = kb + (i64)BATCH * KVC * HW;
    bf16* sb = vb + (i64)BATCH * KVC * HW;
    bf16* qb = sb + (i64)BATCH * KVC * HW;
    float* attn  = (float*)(qb + (i64)BATCH * 512 * HW);
    float* stats = attn + (i64)BATCH * 512 * KVC;

    const dim3 blk(256);
    const float scale = (float)(1.0 / sqrt((double)KVC));

    // ---- K path: kk = wmk * emb_all ; k = dw3x3(kk, wk) ; l2norm(k) ----
    gemm_kernel<float, float, bf16, false><<<dim3(HW/64, KVC/64, BATCH), blk, 0, stream>>>(
        wmk, 0, emb_all, (i64)KVC*HW, sb, (i64)KVC*HW, KVC, HW, KVC, 1.0f);
    dw3x3<<<(BATCH*KVC*HW)/256, blk, 0, stream>>>(sb, wk, kb, KVC);
    l2norm_rows<<<BATCH*KVC, blk, 0, stream>>>(kb);

    // ---- V path ----
    gemm_kernel<float, float, bf16, false><<<dim3(HW/64, KVC/64, BATCH), blk, 0, stream>>>(
        wmv, 0, emb_all, (i64)KVC*HW, sb, (i64)KVC*HW, KVC, HW, KVC, 1.0f);
    dw3x3<<<(BATCH*KVC*HW)/256, blk, 0, stream>>>(sb, wv, vb, KVC);

    // ---- branches ----
    const int CN[4] = {64, 128, 256, 512};
    i64 ooff = 0;
    for (int i = 0; i < 4; ++i) {
        const int c = CN[i];
        // t = wm * emb  -> sb
        gemm_kernel<float, float, bf16, false><<<dim3(HW/64, c/64, BATCH), blk, 0, stream>>>(
            wm[i], 0, emb[i], (i64)c*HW, sb, (i64)c*HW, c, HW, c, 1.0f);
        // q = gconv3x3(t) -> qb ; l2norm
        gconv3x3<<<(BATCH*c*HW)/256, blk, 0, stream>>>(sb, wq[i], qb, c);
        l2norm_rows<<<BATCH*c, blk, 0, stream>>>(qb);
        // attn = scale * q . k^T   (M=c, N=960, K=4096)
        gemm_kernel<bf16, bf16, float, true><<<dim3(KVC/64, c/64, BATCH), blk, 0, stream>>>(
            qb, (i64)c*HW, kb, (i64)KVC*HW, attn, (i64)c*KVC, c, KVC, HW, scale);
        // instance norm stats + softmax (in place on attn)
        inorm_stats<<<BATCH, blk, 0, stream>>>(attn, stats, c*KVC);
        softmax_rows<<<BATCH*c, blk, 0, stream>>>(attn, stats, c);
        // outb = probs . v  (M=c, N=4096, K=960) -> sb
        gemm_kernel<float, bf16, bf16, false><<<dim3(HW/64, c/64, BATCH), blk, 0, stream>>>(
            attn, (i64)c*KVC, vb, (i64)KVC*HW, sb, (i64)c*HW, c, HW, KVC, 1.0f);
        // final = wp . outb -> d_out (fp32)
        gemm_kernel<float, bf16, float, false><<<dim3(HW/64, c/64, BATCH), blk, 0, stream>>>(
            wp[i], 0, sb, (i64)c*HW, out + ooff, (i64)c*HW, c, HW, c, 1.0f);
        ooff += (i64)BATCH * c * HW;
    }
}

// Round 5
// 2916.396 us; speedup vs baseline: 2.0416x; 2.0416x over previous
//
#include <hip/hip_runtime.h>
#include <hip/hip_bf16.h>
#include <math.h>

typedef long long i64;
typedef __hip_bfloat16 bf16;

#define HW 4096
#define KVC 960
#define BATCH 8

using bf8 = __attribute__((ext_vector_type(8))) short;   // 8 bf16 (4 VGPRs)
using f32x4 = __attribute__((ext_vector_type(4))) float; // MFMA accum

__device__ __forceinline__ float bf2f(unsigned short u) {
    union { unsigned int i; float f; } c; c.i = ((unsigned int)u) << 16; return c.f;
}
__device__ __forceinline__ float tof(bf16 v) { return __bfloat162float(v); }
__device__ __forceinline__ short f2bs(float f) {
    bf16 h = __float2bfloat16(f); return *reinterpret_cast<short*>(&h);
}
__device__ __forceinline__ float ld1(const float* p) { return *p; }
__device__ __forceinline__ float ld1(const bf16* p) { return tof(*p); }

// load 4 consecutive elements as bf16 bit-patterns
__device__ __forceinline__ short4 load4b(const float* p) {
    float4 v = *(const float4*)p;
    return make_short4(f2bs(v.x), f2bs(v.y), f2bs(v.z), f2bs(v.w));
}
__device__ __forceinline__ short4 load4b(const bf16* p) {
    ushort4 u = *(const ushort4*)p;
    return make_short4((short)u.x, (short)u.y, (short)u.z, (short)u.w);
}

__device__ __forceinline__ void store1(float* p, float v) { *p = v; }
__device__ __forceinline__ void store1(bf16* p, float v) { *p = __float2bfloat16(v); }

// ---------------------------------------------------------------------------
// MFMA batched GEMM: C[bz] = alpha * A[bz] * B[bz] (optionally B^T).
// A: (M,K) row-major. B: (K,N) row-major, or (N,K) if TRANS_B. C: (M,N).
// K % 32 == 0. M,N arbitrary (clamped loads, guarded stores).
// Tile 128x128, BK=32, 256 threads = 4 waves, each wave 64x64 via 4x4
// mfma_f32_16x16x32_bf16. LDS NT fragment layout: As[m][k], Bs[n][k],
// row stride 40 shorts (pad 8 -> 80B stride, breaks pow2 bank aliasing).
// ---------------------------------------------------------------------------
template<typename TA, typename TB, typename TC, bool TRANS_B>
__global__ __launch_bounds__(256)
void mfma_gemm(const TA* __restrict__ A, i64 aBatch,
               const TB* __restrict__ Bm, i64 bBatch,
               TC* __restrict__ C, i64 cBatch,
               int M, int N, int K, float alpha)
{
    constexpr int LD = 40;  // shorts per LDS row
    __shared__ __align__(16) short As[128 * LD];
    __shared__ __align__(16) short Bs[128 * LD];

    const int bz = blockIdx.z;
    const TA* Ab = A + (i64)bz * aBatch;
    const TB* Bb = Bm + (i64)bz * bBatch;
    const int m0 = blockIdx.y * 128;
    const int n0 = blockIdx.x * 128;
    const int tid  = threadIdx.x;
    const int lane = tid & 63;
    const int wave = tid >> 6;
    const int wm = (wave & 1) * 64;   // wave's 64x64 sub-tile
    const int wn = (wave >> 1) * 64;
    const int quad = lane >> 4;
    const int l16  = lane & 15;

    f32x4 acc[4][4] = {};

    for (int k0 = 0; k0 < K; k0 += 32) {
        // ---- stage A tile: rows m0..m0+127 (clamped), cols k0..k0+31 ----
        #pragma unroll
        for (int p = 0; p < 4; ++p) {
            const int r = p * 32 + (tid >> 3);
            const int c = (tid & 7) * 4;
            int gr = m0 + r; if (gr >= M) gr = M - 1;
            short4 h = load4b(Ab + (i64)gr * K + (k0 + c));
            *(short4*)(As + r * LD + c) = h;
        }
        // ---- stage B tile into Bs[n][k] ----
        if constexpr (TRANS_B) {
            // B is (N,K): direct copy, rows n0..n0+127 (clamped)
            #pragma unroll
            for (int p = 0; p < 4; ++p) {
                const int r = p * 32 + (tid >> 3);
                const int c = (tid & 7) * 4;
                int gr = n0 + r; if (gr >= N) gr = N - 1;
                short4 h = load4b(Bb + (i64)gr * K + (k0 + c));
                *(short4*)(Bs + r * LD + c) = h;
            }
        } else {
            // B is (K,N): transpose 32x128 tile into Bs[n][k]
            #pragma unroll
            for (int p = 0; p < 4; ++p) {
                const int kr = p * 8 + (tid >> 5);
                const int nq = (tid & 31) * 4;
                const i64 base = (i64)(k0 + kr) * N;
                short4 h;
                if (n0 + nq + 3 < N) {
                    h = load4b(Bb + base + n0 + nq);
                } else {
                    int g0 = n0+nq+0; if (g0 >= N) g0 = N-1;
                    int g1 = n0+nq+1; if (g1 >= N) g1 = N-1;
                    int g2 = n0+nq+2; if (g2 >= N) g2 = N-1;
                    int g3 = n0+nq+3; if (g3 >= N) g3 = N-1;
                    h = make_short4(f2bs(ld1(Bb+base+g0)), f2bs(ld1(Bb+base+g1)),
                                    f2bs(ld1(Bb+base+g2)), f2bs(ld1(Bb+base+g3)));
                }
                Bs[(nq+0)*LD + kr] = h.x;
                Bs[(nq+1)*LD + kr] = h.y;
                Bs[(nq+2)*LD + kr] = h.z;
                Bs[(nq+3)*LD + kr] = h.w;
            }
        }
        __syncthreads();

        // ---- fragments + 16 MFMA ----
        bf8 af[4], bfr[4];
        #pragma unroll
        for (int mt = 0; mt < 4; ++mt)
            af[mt] = *(const bf8*)(As + (wm + mt*16 + l16) * LD + quad * 8);
        #pragma unroll
        for (int nt = 0; nt < 4; ++nt)
            bfr[nt] = *(const bf8*)(Bs + (wn + nt*16 + l16) * LD + quad * 8);
        #pragma unroll
        for (int mt = 0; mt < 4; ++mt)
            #pragma unroll
            for (int nt = 0; nt < 4; ++nt)
                acc[mt][nt] = __builtin_amdgcn_mfma_f32_16x16x32_bf16(
                    af[mt], bfr[nt], acc[mt][nt], 0, 0, 0);
        __syncthreads();
    }

    // ---- epilogue: C/D layout col=lane&15, row=quad*4+reg ----
    const i64 cb = (i64)bz * cBatch;
    #pragma unroll
    for (int mt = 0; mt < 4; ++mt) {
        #pragma unroll
        for (int r = 0; r < 4; ++r) {
            const int row = m0 + wm + mt*16 + quad*4 + r;
            if (row >= M) continue;
            const i64 rb = cb + (i64)row * N;
            #pragma unroll
            for (int nt = 0; nt < 4; ++nt) {
                const int col = n0 + wn + nt*16 + l16;
                if (col < N) store1(C + rb + col, alpha * acc[mt][nt][r]);
            }
        }
    }
}

// ---------------------------------------------------------------------------
// Depthwise 3x3 SAME, NCHW 64x64 images. fp32 weights, bf16 act in/out.
// ---------------------------------------------------------------------------
__global__ __launch_bounds__(256)
void dw3x3(const bf16* __restrict__ in, const float* __restrict__ w,
           bf16* __restrict__ out, int C)
{
    const int idx = blockIdx.x * 256 + threadIdx.x;
    const int p = idx & 4095;
    const int bch = idx >> 12;
    const int c = bch % C;
    const int x = p & 63, y = p >> 6;
    const float* wp = w + c * 9;
    const bf16* ip = in + (i64)bch * HW;
    float s = 0.f;
    #pragma unroll
    for (int dy = -1; dy <= 1; ++dy) {
        const int yy = y + dy;
        if (yy < 0 || yy > 63) continue;
        #pragma unroll
        for (int dx = -1; dx <= 1; ++dx) {
            const int xx = x + dx;
            if (xx < 0 || xx > 63) continue;
            s = fmaf(wp[(dy+1)*3 + (dx+1)], tof(ip[yy*64 + xx]), s);
        }
    }
    out[idx] = __float2bfloat16(s);
}

// ---------------------------------------------------------------------------
// Grouped 3x3 SAME, groups=C/2 (2 in, 2 out per group). w: (C,2,3,3)
// ---------------------------------------------------------------------------
__global__ __launch_bounds__(256)
void gconv3x3(const bf16* __restrict__ in, const float* __restrict__ w,
              bf16* __restrict__ out, int C)
{
    const int idx = blockIdx.x * 256 + threadIdx.x;
    const int p = idx & 4095;
    const int bch = idx >> 12;
    const int c = bch % C;
    const int b = bch / C;
    const int x = p & 63, y = p >> 6;
    const float* wp = w + c * 18;
    const bf16* i0 = in + ((i64)b * C + (c & ~1)) * HW;
    float s = 0.f;
    #pragma unroll
    for (int j = 0; j < 2; ++j) {
        #pragma unroll
        for (int dy = -1; dy <= 1; ++dy) {
            const int yy = y + dy;
            if (yy < 0 || yy > 63) continue;
            #pragma unroll
            for (int dx = -1; dx <= 1; ++dx) {
                const int xx = x + dx;
                if (xx < 0 || xx > 63) continue;
                s = fmaf(wp[j*9 + (dy+1)*3 + (dx+1)], tof(i0[(i64)j*HW + yy*64 + xx]), s);
            }
        }
    }
    out[idx] = __float2bfloat16(s);
}

// ---------------------------------------------------------------------------
// Per-row L2 normalize (rows of length 4096), bf16 in place.
// ---------------------------------------------------------------------------
__global__ __launch_bounds__(256)
void l2norm_rows(bf16* __restrict__ x)
{
    const i64 base = (i64)blockIdx.x * HW;
    float ss = 0.f;
    for (int i = threadIdx.x; i < HW; i += 256) {
        const float v = tof(x[base + i]);
        ss = fmaf(v, v, ss);
    }
    #pragma unroll
    for (int o = 32; o > 0; o >>= 1) ss += __shfl_down(ss, o);
    __shared__ float red[4];
    __shared__ float sinv;
    const int lane = threadIdx.x & 63, wid = threadIdx.x >> 6;
    if (lane == 0) red[wid] = ss;
    __syncthreads();
    if (threadIdx.x == 0) {
        float t = red[0] + red[1] + red[2] + red[3];
        t = fmaxf(sqrtf(t), 1e-12f);
        sinv = 1.0f / t;
    }
    __syncthreads();
    const float inv = sinv;
    for (int i = threadIdx.x; i < HW; i += 256)
        x[base + i] = __float2bfloat16(tof(x[base + i]) * inv);
}

// ---------------------------------------------------------------------------
// Instance-norm stats, two stage. Stage 1: grid (BATCH, NCH) partials.
// ---------------------------------------------------------------------------
#define NCH 32
__global__ __launch_bounds__(256)
void inorm_partial(const float* __restrict__ a, float* __restrict__ part, int n)
{
    const int b = blockIdx.x, ch = blockIdx.y;
    const int per = n / NCH;            // n = c*960, divisible by 32
    const i64 base = (i64)b * n + (i64)ch * per;
    float s = 0.f, s2 = 0.f;
    for (int i = threadIdx.x; i < per; i += 256) {
        const float v = a[base + i];
        s += v;
        s2 = fmaf(v, v, s2);
    }
    #pragma unroll
    for (int o = 32; o > 0; o >>= 1) {
        s  += __shfl_down(s, o);
        s2 += __shfl_down(s2, o);
    }
    __shared__ float r1[4], r2[4];
    const int lane = threadIdx.x & 63, wid = threadIdx.x >> 6;
    if (lane == 0) { r1[wid] = s; r2[wid] = s2; }
    __syncthreads();
    if (threadIdx.x == 0) {
        part[(b * NCH + ch) * 2 + 0] = r1[0] + r1[1] + r1[2] + r1[3];
        part[(b * NCH + ch) * 2 + 1] = r2[0] + r2[1] + r2[2] + r2[3];
    }
}

__global__ __launch_bounds__(64)
void inorm_finish(const float* __restrict__ part, float* __restrict__ stats, int n)
{
    const int b = blockIdx.x;
    const int i = threadIdx.x;
    float s  = (i < NCH) ? part[(b * NCH + i) * 2 + 0] : 0.f;
    float s2 = (i < NCH) ? part[(b * NCH + i) * 2 + 1] : 0.f;
    #pragma unroll
    for (int o = 32; o > 0; o >>= 1) {
        s  += __shfl_down(s, o);
        s2 += __shfl_down(s2, o);
    }
    if (i == 0) {
        const float mu = s / (float)n;
        const float var = s2 / (float)n - mu * mu;
        stats[b * 2 + 0] = mu;
        stats[b * 2 + 1] = rsqrtf(var + 1e-5f);
    }
}

// ---------------------------------------------------------------------------
// Row softmax over KV=960 after instance-norm transform, in place (fp32).
// ---------------------------------------------------------------------------
__global__ __launch_bounds__(256)
void softmax_rows(float* __restrict__ a, const float* __restrict__ stats, int c)
{
    const int row = blockIdx.x;
    const int b = row / c;
    const i64 base = (i64)row * KVC;
    const float mu = stats[b*2 + 0];
    const float rs = stats[b*2 + 1];
    float vals[4];
    float mx = -1e30f;
    #pragma unroll
    for (int t = 0; t < 4; ++t) {
        const int i = threadIdx.x + t * 256;
        float v = -1e30f;
        if (i < KVC) v = (a[base + i] - mu) * rs;
        vals[t] = v;
        mx = fmaxf(mx, v);
    }
    #pragma unroll
    for (int o = 32; o > 0; o >>= 1) mx = fmaxf(mx, __shfl_down(mx, o));
    __shared__ float red[4];
    __shared__ float bmx, bsum;
    const int lane = threadIdx.x & 63, wid = threadIdx.x >> 6;
    if (lane == 0) red[wid] = mx;
    __syncthreads();
    if (threadIdx.x == 0) bmx = fmaxf(fmaxf(red[0], red[1]), fmaxf(red[2], red[3]));
    __syncthreads();
    const float M = bmx;
    float se = 0.f;
    #pragma unroll
    for (int t = 0; t < 4; ++t) {
        const int i = threadIdx.x + t * 256;
        if (i < KVC) { vals[t] = expf(vals[t] - M); se += vals[t]; }
    }
    #pragma unroll
    for (int o = 32; o > 0; o >>= 1) se += __shfl_down(se, o);
    if (lane == 0) red[wid] = se;
    __syncthreads();
    if (threadIdx.x == 0) bsum = red[0] + red[1] + red[2] + red[3];
    __syncthreads();
    const float S = bsum;
    #pragma unroll
    for (int t = 0; t < 4; ++t) {
        const int i = threadIdx.x + t * 256;
        if (i < KVC) a[base + i] = vals[t] / S;
    }
}

// ---------------------------------------------------------------------------
extern "C" void kernel_launch(void* const* d_in, const int* in_sizes, int n_in,
                              void* d_out, int out_size, void* d_ws, size_t ws_size,
                              hipStream_t stream)
{
    (void)in_sizes; (void)n_in; (void)out_size; (void)ws_size;

    const float* emb[4]  = {(const float*)d_in[0], (const float*)d_in[1],
                            (const float*)d_in[2], (const float*)d_in[3]};
    const float* emb_all = (const float*)d_in[4];
    const float* wm[4]   = {(const float*)d_in[5], (const float*)d_in[8],
                            (const float*)d_in[11], (const float*)d_in[14]};
    const float* wq[4]   = {(const float*)d_in[6], (const float*)d_in[9],
                            (const float*)d_in[12], (const float*)d_in[15]};
    const float* wp[4]   = {(const float*)d_in[7], (const float*)d_in[10],
                            (const float*)d_in[13], (const float*)d_in[16]};
    const float* wmk = (const float*)d_in[17];
    const float* wmv = (const float*)d_in[18];
    const float* wk  = (const float*)d_in[19];
    const float* wv  = (const float*)d_in[20];
    float* out = (float*)d_out;   // fp32 output (confirmed round 4)

    // workspace: kb/vb/sb bf16 62.9MB each, qb bf16 33.5MB, attn fp32 15.7MB
    bf16* kb = (bf16*)d_ws;
    bf16* vb = kb + (i64)BATCH * KVC * HW;
    bf16* sb = vb + (i64)BATCH * KVC * HW;
    bf16* qb = sb + (i64)BATCH * KVC * HW;
    float* attn  = (float*)(qb + (i64)BATCH * 512 * HW);
    float* part  = attn + (i64)BATCH * 512 * KVC;
    float* stats = part + BATCH * NCH * 2;

    const dim3 blk(256);
    const float scale = (float)(1.0 / sqrt((double)KVC));

    // ---- K path: kk = wmk*emb_all ; k = dw3x3 ; l2norm ----
    mfma_gemm<float, float, bf16, false><<<dim3(HW/128, 8, BATCH), blk, 0, stream>>>(
        wmk, 0, emb_all, (i64)KVC*HW, sb, (i64)KVC*HW, KVC, HW, KVC, 1.0f);
    dw3x3<<<(BATCH*KVC*HW)/256, blk, 0, stream>>>(sb, wk, kb, KVC);
    l2norm_rows<<<BATCH*KVC, blk, 0, stream>>>(kb);

    // ---- V path ----
    mfma_gemm<float, float, bf16, false><<<dim3(HW/128, 8, BATCH), blk, 0, stream>>>(
        wmv, 0, emb_all, (i64)KVC*HW, sb, (i64)KVC*HW, KVC, HW, KVC, 1.0f);
    dw3x3<<<(BATCH*KVC*HW)/256, blk, 0, stream>>>(sb, wv, vb, KVC);

    // ---- branches ----
    const int CN[4] = {64, 128, 256, 512};
    i64 ooff = 0;
    for (int i = 0; i < 4; ++i) {
        const int c = CN[i];
        const int mt = (c + 127) / 128;
        // t = wm * emb -> sb
        mfma_gemm<float, float, bf16, false><<<dim3(HW/128, mt, BATCH), blk, 0, stream>>>(
            wm[i], 0, emb[i], (i64)c*HW, sb, (i64)c*HW, c, HW, c, 1.0f);
        // q = gconv3x3(t) -> qb ; l2norm
        gconv3x3<<<(BATCH*c*HW)/256, blk, 0, stream>>>(sb, wq[i], qb, c);
        l2norm_rows<<<BATCH*c, blk, 0, stream>>>(qb);
        // attn = scale * q . k^T   (M=c, N=960, K=4096; B=(N,K) -> TRANS_B)
        mfma_gemm<bf16, bf16, float, true><<<dim3((KVC+127)/128, mt, BATCH), blk, 0, stream>>>(
            qb, (i64)c*HW, kb, (i64)KVC*HW, attn, (i64)c*KVC, c, KVC, HW, scale);
        // instance norm stats + softmax (in place on attn)
        inorm_partial<<<dim3(BATCH, NCH), blk, 0, stream>>>(attn, part, c*KVC);
        inorm_finish<<<BATCH, 64, 0, stream>>>(part, stats, c*KVC);
        softmax_rows<<<BATCH*c, blk, 0, stream>>>(attn, stats, c);
        // outb = probs . v -> sb   (M=c, N=4096, K=960)
        mfma_gemm<float, bf16, bf16, false><<<dim3(HW/128, mt, BATCH), blk, 0, stream>>>(
            attn, (i64)c*KVC, vb, (i64)KVC*HW, sb, (i64)c*HW, c, HW, KVC, 1.0f);
        // final = wp . outb -> out (fp32)
        mfma_gemm<float, bf16, float, false><<<dim3(HW/128, mt, BATCH), blk, 0, stream>>>(
            wp[i], 0, sb, (i64)c*HW, out + ooff, (i64)c*HW, c, HW, c, 1.0f);
        ooff += (i64)BATCH * c * HW;
    }
}